// Round 9
// baseline (378.036 us; speedup 1.0000x reference)
//
#include <hip/hip_runtime.h>

// Problem constants
#define BB 16
#define CC 256
#define RR 16
#define HWPLANE 16384              // 128*128 floats per (b,c) plane
#define NBLOCKS 512
#define NSTAGES 8                  // 2 batches per stage
#define PLANES_PER_STAGE 512
#define COHORT 256                 // blocks per batch cohort

using f32x4 = __attribute__((ext_vector_type(4))) float;

// ---------------------------------------------------------------------------
// Init: zero the 16 per-(stage,batch) cohort counters (ws is 0xAA-poisoned
// once; graph replays re-run this each call so every replay starts from 0).
// ---------------------------------------------------------------------------
__global__ void init_kernel(unsigned* bar) {
    if (threadIdx.x < 16) bar[threadIdx.x] = 0u;
}

// Cohort barrier (256 blocks of one batch). RELEASE on the increment orders
// the producer's fused[] atomic store; polls are RELAXED (no cache
// invalidates -- R3/R4's poison); NO acquire fence: all cross-block data
// moves via agent-scope atomics that execute at the coherence point.
__device__ __forceinline__ void cohort_barrier(unsigned* cnt) {
    __syncthreads();
    if (threadIdx.x == 0) {
        __hip_atomic_fetch_add(cnt, 1u, __ATOMIC_RELEASE,
                               __HIP_MEMORY_SCOPE_AGENT);
        unsigned v;
        do {
            __builtin_amdgcn_s_sleep(8);
            v = __hip_atomic_load(cnt, __ATOMIC_RELAXED,
                                  __HIP_MEMORY_SCOPE_AGENT);
        } while (v < COHORT);
    }
    __syncthreads();
}

// ---------------------------------------------------------------------------
// Persistent kernel, one block per plane per stage, plane held in REGISTERS
// (16 float4 per thread) across pool -> barrier -> SE -> scale, so x is read
// from HBM exactly once (512 MiB total traffic: 256 read + 256 write).
// ---------------------------------------------------------------------------
__global__ __launch_bounds__(256) void spse_persist_kernel(
    const float* __restrict__ x,
    const float* __restrict__ Wf,   // (C, 21)
    const float* __restrict__ bf,   // (C,)
    const float* __restrict__ W1,   // (C, r)
    const float* __restrict__ b1,   // (r,)
    const float* __restrict__ W2,   // (r, C)
    const float* __restrict__ b2,   // (C,)
    float* __restrict__ out,
    unsigned* __restrict__ bar,     // 16 counters: [stage*2 + batchInStage]
    float* __restrict__ fused)      // (B*C,)
{
    const int t    = threadIdx.x;
    const int lane = t & 63;
    const int wave = t >> 6;
    const int bx   = (t & 31) >> 3;
    const int blk  = blockIdx.x;

    __shared__ float wred[4][16];
    __shared__ float pb[16];
    __shared__ float fl[CC];          // fused[b,:] staged once per block
    __shared__ float hpart[16][16];
    __shared__ float hl[RR];
    __shared__ float svs;

    for (int s = 0; s < NSTAGES; ++s) {
        const int bc = s * PLANES_PER_STAGE + blk;
        const int b  = bc >> 8;
        const int c  = bc & (CC - 1);
        const f32x4* xp = (const f32x4*)(x + (size_t)bc * HWPLANE);
        f32x4* op = (f32x4*)(out + (size_t)bc * HWPLANE);

        // ---- load own plane into registers (NT: nothing needs it cached) ----
        f32x4 v[16];
#pragma unroll
        for (int i = 0; i < 16; ++i)
            v[i] = __builtin_nontemporal_load(&xp[i * 256 + t]);

        // ---- hierarchical block maxes from registers ----
#pragma unroll
        for (int by = 0; by < 4; ++by) {
            float m = -3.402823466e+38f;
#pragma unroll
            for (int ii = 0; ii < 4; ++ii) {
                f32x4 w4 = v[by * 4 + ii];
                m = fmaxf(m, fmaxf(fmaxf(w4.x, w4.y), fmaxf(w4.z, w4.w)));
            }
            m = fmaxf(m, __shfl_xor(m, 1));
            m = fmaxf(m, __shfl_xor(m, 2));
            m = fmaxf(m, __shfl_xor(m, 4));
            m = fmaxf(m, __shfl_xor(m, 32));
            if ((lane & 7) == 0 && lane < 32) wred[wave][by * 4 + bx] = m;
        }
        __syncthreads();
        if (t < 16)
            pb[t] = fmaxf(fmaxf(wred[0][t], wred[1][t]),
                          fmaxf(wred[2][t], wred[3][t]));
        __syncthreads();

        // ---- fused 21->1 linear, atomic store (coherence point) ----
        if (t == 0) {
            float q0 = fmaxf(fmaxf(pb[0],  pb[1]),  fmaxf(pb[4],  pb[5]));
            float q1 = fmaxf(fmaxf(pb[2],  pb[3]),  fmaxf(pb[6],  pb[7]));
            float q2 = fmaxf(fmaxf(pb[8],  pb[9]),  fmaxf(pb[12], pb[13]));
            float q3 = fmaxf(fmaxf(pb[10], pb[11]), fmaxf(pb[14], pb[15]));
            float g  = fmaxf(fmaxf(q0, q1), fmaxf(q2, q3));
            const float* w = Wf + c * 21;
            float acc = bf[c] + g * w[0]
                      + q0 * w[1] + q1 * w[2] + q2 * w[3] + q3 * w[4];
#pragma unroll
            for (int k = 0; k < 16; ++k) acc += pb[k] * w[5 + k];
            __hip_atomic_store(&fused[bc], acc, __ATOMIC_RELAXED,
                               __HIP_MEMORY_SCOPE_AGENT);
        }

        // ---- wait for the 256 blocks of OUR batch ----
        cohort_barrier(&bar[s * 2 + (blk >> 8)]);

        // ---- stage fused[b,:] into LDS: ONE atomic load per thread ----
        fl[t] = __hip_atomic_load(&fused[b * CC + t], __ATOMIC_RELAXED,
                                  __HIP_MEMORY_SCOPE_AGENT);
        __syncthreads();

        // ---- redundant per-block SE from LDS ----
        {
            const int j = t & 15, ch = t >> 4;
            float p = 0.f;
#pragma unroll
            for (int m = 0; m < 16; ++m)
                p += fl[ch * 16 + m] * W1[(ch * 16 + m) * RR + j];
            hpart[ch][j] = p;
        }
        __syncthreads();
        if (t < RR) {
            float a = b1[t];
#pragma unroll
            for (int ch = 0; ch < 16; ++ch) a += hpart[ch][t];
            hl[t] = fmaxf(a, 0.f);
        }
        __syncthreads();
        if (t == 0) {
            float a = b2[c];
#pragma unroll
            for (int j = 0; j < RR; ++j) a += hl[j] * W2[j * CC + c];
            svs = a;
        }
        __syncthreads();

        // ---- scale from registers, NT store ----
        const float sc = svs;
#pragma unroll
        for (int i = 0; i < 16; ++i)
            __builtin_nontemporal_store(v[i] * sc, &op[i * 256 + t]);

        __syncthreads();   // protect shared arrays before next stage reuses
    }
}

extern "C" void kernel_launch(void* const* d_in, const int* in_sizes, int n_in,
                              void* d_out, int out_size, void* d_ws, size_t ws_size,
                              hipStream_t stream) {
    const float* x  = (const float*)d_in[0];
    const float* Wf = (const float*)d_in[1];
    const float* bf = (const float*)d_in[2];
    const float* W1 = (const float*)d_in[3];
    const float* b1 = (const float*)d_in[4];
    const float* W2 = (const float*)d_in[5];
    const float* b2 = (const float*)d_in[6];
    float* out = (float*)d_out;

    unsigned* bar = (unsigned*)d_ws;
    float* fused  = (float*)((char*)d_ws + 256);   // B*C floats

    init_kernel<<<1, 64, 0, stream>>>(bar);
    spse_persist_kernel<<<NBLOCKS, 256, 0, stream>>>(
        x, Wf, bf, W1, b1, W2, b2, out, bar, fused);
}

// Round 10
// 136.226 us; speedup vs baseline: 2.7751x; 2.7751x over previous
//
#include <hip/hip_runtime.h>

// Problem constants
#define BB 16
#define CC 256
#define RR 16
#define HWPLANE 16384              // 128*128 floats per (b,c) plane
#define NGROUPS 4                  // 4 batches per group
#define PLANES_PER_GROUP 1024      // 4 * 256

using f32x4 = __attribute__((ext_vector_type(4))) float;

// ---------------------------------------------------------------------------
// Role-split stage kernel.
//   blocks [0, n_scale)            : SE + scale of plane scale_plane0+i
//   blocks [n_scale, n_scale+n_pool): pool of plane pool_plane0+(i-n_scale)
// Scale and pool run CONCURRENTLY across the dispatch (each CU hosts ~4 of
// each role), overlapping the HBM cold-read stream (pool) with the NT write
// stream (scale), while scale's x re-read hits L3 via nontemporal loads
// (no L2 pollution of the pool prefetch).
// Chain: pool0 | s0+p1 | s1+p2 | s2+p3 | s3   (5 stream-ordered dispatches)
// ---------------------------------------------------------------------------
__global__ __launch_bounds__(256) void spse_stage_kernel(
    const float* __restrict__ x,
    const float* __restrict__ Wf,   // (C, 21)
    const float* __restrict__ bf,   // (C,)
    const float* __restrict__ W1,   // (C, r)
    const float* __restrict__ b1,   // (r,)
    const float* __restrict__ W2,   // (r, C)
    const float* __restrict__ b2,   // (C,)
    float* __restrict__ fused,      // (B*C,)
    float* __restrict__ out,
    int scale_plane0,
    int n_scale,                    // blocks below this do scale, above pool
    int pool_plane0)
{
    const int t = threadIdx.x;

    if ((int)blockIdx.x < n_scale) {
        // ================= SCALE role =================
        const int bc = scale_plane0 + blockIdx.x;
        const int b  = bc >> 8;
        const int c  = bc & (CC - 1);

        __shared__ float hpart[16][16];
        __shared__ float hl[RR];
        __shared__ float svs;

        {   // h partials: thread (ch, j) accumulates 16 channels
            const int j = t & 15, ch = t >> 4;
            float p = 0.f;
#pragma unroll
            for (int m = 0; m < 16; ++m) {
                const int cc = ch * 16 + m;
                p += fused[b * CC + cc] * W1[cc * RR + j];
            }
            hpart[ch][j] = p;
        }
        __syncthreads();
        if (t < RR) {
            float a = b1[t];
#pragma unroll
            for (int ch = 0; ch < 16; ++ch) a += hpart[ch][t];
            hl[t] = fmaxf(a, 0.f);
        }
        __syncthreads();
        if (t == 0) {
            float a = b2[c];
#pragma unroll
            for (int j = 0; j < RR; ++j) a += hl[j] * W2[j * CC + c];
            svs = a;
        }
        __syncthreads();

        const float sc = svs;
        const f32x4* xp = (const f32x4*)(x + (size_t)bc * HWPLANE);
        f32x4* op = (f32x4*)(out + (size_t)bc * HWPLANE);
#pragma unroll
        for (int i = 0; i < 16; ++i) {
            f32x4 v = __builtin_nontemporal_load(&xp[i * 256 + t]);
            __builtin_nontemporal_store(v * sc, &op[i * 256 + t]);
        }
    } else if (pool_plane0 >= 0) {
        // ================= POOL role =================
        const int bc = pool_plane0 + ((int)blockIdx.x - n_scale);
        const int c  = bc & (CC - 1);
        const f32x4* xp = (const f32x4*)(x + (size_t)bc * HWPLANE);

        const int lane = t & 63;
        const int wave = t >> 6;
        const int bx   = (t & 31) >> 3;

        __shared__ float wred[4][16];
        __shared__ float pb[16];

#pragma unroll
        for (int by = 0; by < 4; ++by) {
            float m = -3.402823466e+38f;
#pragma unroll
            for (int ii = 0; ii < 4; ++ii) {
                f32x4 v = xp[(by * 4 + ii) * 256 + t];
                m = fmaxf(m, fmaxf(fmaxf(v.x, v.y), fmaxf(v.z, v.w)));
            }
            m = fmaxf(m, __shfl_xor(m, 1));
            m = fmaxf(m, __shfl_xor(m, 2));
            m = fmaxf(m, __shfl_xor(m, 4));
            m = fmaxf(m, __shfl_xor(m, 32));
            if ((lane & 7) == 0 && lane < 32) wred[wave][by * 4 + bx] = m;
        }
        __syncthreads();

        if (t < 16)
            pb[t] = fmaxf(fmaxf(wred[0][t], wred[1][t]),
                          fmaxf(wred[2][t], wred[3][t]));
        __syncthreads();

        if (t == 0) {
            float q0 = fmaxf(fmaxf(pb[0],  pb[1]),  fmaxf(pb[4],  pb[5]));
            float q1 = fmaxf(fmaxf(pb[2],  pb[3]),  fmaxf(pb[6],  pb[7]));
            float q2 = fmaxf(fmaxf(pb[8],  pb[9]),  fmaxf(pb[12], pb[13]));
            float q3 = fmaxf(fmaxf(pb[10], pb[11]), fmaxf(pb[14], pb[15]));
            float g  = fmaxf(fmaxf(q0, q1), fmaxf(q2, q3));

            const float* w = Wf + c * 21;
            float acc = bf[c] + g * w[0]
                      + q0 * w[1] + q1 * w[2] + q2 * w[3] + q3 * w[4];
#pragma unroll
            for (int k = 0; k < 16; ++k) acc += pb[k] * w[5 + k];
            fused[bc] = acc;
        }
    }
}

extern "C" void kernel_launch(void* const* d_in, const int* in_sizes, int n_in,
                              void* d_out, int out_size, void* d_ws, size_t ws_size,
                              hipStream_t stream) {
    const float* x  = (const float*)d_in[0];
    const float* Wf = (const float*)d_in[1];
    const float* bf = (const float*)d_in[2];
    const float* W1 = (const float*)d_in[3];
    const float* b1 = (const float*)d_in[4];
    const float* W2 = (const float*)d_in[5];
    const float* b2 = (const float*)d_in[6];
    float* out = (float*)d_out;

    float* fused = (float*)d_ws;          // B*C floats

    // pool0 (1024 pool blocks, no scale)
    spse_stage_kernel<<<PLANES_PER_GROUP, 256, 0, stream>>>(
        x, Wf, bf, W1, b1, W2, b2, fused, out, 0, 0, 0);
    // scale(g) blocks 0..1023  ||  pool(g+1) blocks 1024..2047
    for (int g = 0; g < NGROUPS - 1; ++g) {
        spse_stage_kernel<<<2 * PLANES_PER_GROUP, 256, 0, stream>>>(
            x, Wf, bf, W1, b1, W2, b2, fused, out,
            g * PLANES_PER_GROUP, PLANES_PER_GROUP,
            (g + 1) * PLANES_PER_GROUP);
    }
    // scale3 (1024 scale blocks, no pool)
    spse_stage_kernel<<<PLANES_PER_GROUP, 256, 0, stream>>>(
        x, Wf, bf, W1, b1, W2, b2, fused, out,
        (NGROUPS - 1) * PLANES_PER_GROUP, PLANES_PER_GROUP, -1);
}